// Round 6
// baseline (126.970 us; speedup 1.0000x reference)
//
#include <hip/hip_runtime.h>
#include <float.h>

// Problem constants (match reference)
#define BB 32
#define CC 256
#define SS 64
#define IMG (SS * SS)          // 4096 pixels per (b,c) image
#define NPIX (BB * IMG)
#define NTOT (BB * CC * IMG)   // 33554432 total elements

typedef float f32x4 __attribute__((ext_vector_type(4)));

// ws layout (float offsets)
#define WPM_OFF 0              // wpart_max[32][16][64]  (per-block col-max partials)
#define WPS_OFF 32768          // wpart_sum[32][16][64]  (per-block col-sum-of-mean partials)
#define HMX_OFF 65536          // hmax[32][64]           (complete per-row max)
#define HSM_OFF 67584          // hsum[32][64]           (complete per-row sum-of-mean)
#define SPA_OFF 69632          // spatial[32][4096]
#define CNT_BYTE_OFF ((SPA_OFF + NPIX) * 4)   // int cnt[32], zeroed each launch

__device__ __forceinline__ f32x4 f4max(f32x4 a, f32x4 b) {
    f32x4 r;
    r.x = fmaxf(a.x, b.x); r.y = fmaxf(a.y, b.y);
    r.z = fmaxf(a.z, b.z); r.w = fmaxf(a.w, b.w);
    return r;
}
__device__ __forceinline__ f32x4 shfl_xor4(f32x4 v, int m) {
    f32x4 r;
    r.x = __shfl_xor(v.x, m); r.y = __shfl_xor(v.y, m);
    r.z = __shfl_xor(v.z, m); r.w = __shfl_xor(v.w, m);
    return r;
}

__device__ __forceinline__ float allreduce_sum(float v) {
#pragma unroll
    for (int o = 32; o > 0; o >>= 1) v += __shfl_xor(v, o);
    return v;
}
__device__ __forceinline__ float allreduce_max(float v) {
#pragma unroll
    for (int o = 32; o > 0; o >>= 1) v = fmaxf(v, __shfl_xor(v, o));
    return v;
}

__device__ __forceinline__ float branch_lane(float meanv, float maxv,
                                             float w0, float w1, float w2,
                                             float b0, float b1, float b2) {
    float m  = allreduce_max(meanv);
    float e  = expf(meanv - m);
    float s  = e / allreduce_sum(e);
    float y0 = allreduce_sum(meanv * w0);
    float y1 = allreduce_sum(maxv * w1);
    float y0t = tanhf(fmaf(y0, s, b0));
    float y1t = tanhf(fmaf(y1, s, b1));
    float yw2 = allreduce_sum(y1t * w2);
    return fmaf(yw2, y0t, b2);
}

// ---------------- Kernel A: channel reduction + (last block) branch ----------------
// 512 blocks: (b = blk>>4, j = blk&15). Block owns pixels [j*256, j*256+256)
// = image rows 4j..4j+3 of batch b. Wave w reduces channels [w*64, w*64+64).
// Wave 0 merges, emits height rows (complete) and width col-partials, then the
// 16th-arriving block of each batch runs the branch math and writes spatial.
__global__ __launch_bounds__(256) void reduce_branch_kernel(
        const float* __restrict__ x,
        const float* __restrict__ ww0, const float* __restrict__ ww1, const float* __restrict__ ww2,
        const float* __restrict__ wb0, const float* __restrict__ wb1, const float* __restrict__ wb2,
        const float* __restrict__ hw0, const float* __restrict__ hw1, const float* __restrict__ hw2,
        const float* __restrict__ hb0, const float* __restrict__ hb1, const float* __restrict__ hb2,
        float* __restrict__ ws, int* __restrict__ cnt) {
    const int blk  = blockIdx.x;
    const int b    = blk >> 4;
    const int j    = blk & 15;
    const int tid  = threadIdx.x;
    const int wave = tid >> 6;
    const int lane = tid & 63;
    const int pos0 = j << 8;                         // 256 px = rows 4j..4j+3

    const float* xp = x + ((size_t)(b * CC + wave * 64) << 12) + pos0 + (lane << 2);
    f32x4 vmax = (f32x4)(-FLT_MAX);
    f32x4 vsum = (f32x4)(0.f);
#pragma unroll 16
    for (int c = 0; c < 64; ++c) {
        f32x4 v = *(const f32x4*)(xp + ((size_t)c << 12));
        vmax = f4max(vmax, v);
        vsum += v;
    }

    __shared__ f32x4 smax[4][64];
    __shared__ f32x4 ssum[4][64];
    __shared__ float sh_w[64], sh_h[64];
    __shared__ int islast;
    smax[wave][lane] = vmax;
    ssum[wave][lane] = vsum;
    __syncthreads();

    if (wave == 0) {
        f32x4 m = smax[0][lane];
        f32x4 s = ssum[0][lane];
#pragma unroll
        for (int w = 1; w < 4; ++w) {
            m = f4max(m, smax[w][lane]);
            s += ssum[w][lane];
        }
        f32x4 mean = s * (1.0f / (float)CC);

        // lane l holds pixels [4l..4l+3]: row r = l>>4 (global 4j+r), cols (l&15)*4+k
        // Height (complete rows): reduce over the 16 lanes of each row group.
        float em = fmaxf(fmaxf(m.x, m.y), fmaxf(m.z, m.w));
        float es = mean.x + mean.y + mean.z + mean.w;
#pragma unroll
        for (int o = 1; o < 16; o <<= 1) {
            em = fmaxf(em, __shfl_xor(em, o));
            es += __shfl_xor(es, o);
        }
        if ((lane & 15) == 0) {
            const int row = 4 * j + (lane >> 4);
            ws[HMX_OFF + b * 64 + row] = em;
            ws[HSM_OFF + b * 64 + row] = es;
        }
        // Width partials (over this block's 4 rows): reduce across row groups.
        f32x4 cm = m, cs = mean;
        cm = f4max(cm, shfl_xor4(cm, 16));
        cm = f4max(cm, shfl_xor4(cm, 32));
        cs += shfl_xor4(cs, 16);
        cs += shfl_xor4(cs, 32);
        if (lane < 16) {
            *(f32x4*)(ws + WPM_OFF + (b * 16 + j) * 64 + lane * 4) = cm;
            *(f32x4*)(ws + WPS_OFF + (b * 16 + j) * 64 + lane * 4) = cs;
        }
    }
    __syncthreads();                 // drains all vmem (compiler emits vmcnt(0) before barrier)
    __threadfence();                 // release: make partials device-visible
    if (tid == 0) islast = (atomicAdd(&cnt[b], 1) == 15) ? 1 : 0;
    __syncthreads();
    if (!islast) return;

    __threadfence();                 // acquire side
    if (wave == 0) {
        float wm = -FLT_MAX, wsv = 0.f;
#pragma unroll
        for (int j2 = 0; j2 < 16; ++j2) {
            wm = fmaxf(wm, ws[WPM_OFF + (b * 16 + j2) * 64 + lane]);
            wsv += ws[WPS_OFF + (b * 16 + j2) * 64 + lane];
        }
        sh_w[lane] = branch_lane(wsv * (1.0f / (float)SS), wm,
                                 ww0[lane], ww1[lane], ww2[lane],
                                 wb0[lane], wb1[lane], wb2[lane]);
    } else if (wave == 1) {
        float hm = ws[HMX_OFF + b * 64 + lane];
        float hs = ws[HSM_OFF + b * 64 + lane];
        sh_h[lane] = branch_lane(hs * (1.0f / (float)SS), hm,
                                 hw0[lane], hw1[lane], hw2[lane],
                                 hb0[lane], hb1[lane], hb2[lane]);
    }
    __syncthreads();
    float* sp = ws + SPA_OFF + (size_t)b * IMG;
#pragma unroll 4
    for (int p = tid; p < IMG; p += 256) {
        sp[p] = tanhf(sh_h[p >> 6] * sh_w[p & 63]);   // coalesced
    }
}

// ---------------- Kernel B: apply ----------------
// NT stores: streaming output shouldn't evict x from L3. 2x-unrolled
// independent loads for deeper MLP.
__global__ __launch_bounds__(256) void apply_kernel(const float* __restrict__ x,
                                                    const float* __restrict__ spatial,
                                                    float* __restrict__ out) {
    const int nPairs = NTOT / 8;
    const int stride = gridDim.x * blockDim.x;
    for (int i = blockIdx.x * blockDim.x + threadIdx.x; i < nPairs; i += stride) {
        const size_t e = (size_t)i << 3;               // float index (multiple of 8)
        f32x4 xa = ((const f32x4*)x)[2 * (size_t)i];
        f32x4 xb = ((const f32x4*)x)[2 * (size_t)i + 1];
        const size_t b   = e >> 20;                    // / (C*IMG)
        const size_t pos = e & (IMG - 1);              // within image (no 8-crossing: IMG%8==0)
        const float* spp = spatial + (b << 12) + pos;
        f32x4 sa = *(const f32x4*)(spp);
        f32x4 sb = *(const f32x4*)(spp + 4);
        __builtin_nontemporal_store(xa * (sa + 1.0f), ((f32x4*)out) + 2 * (size_t)i);
        __builtin_nontemporal_store(xb * (sb + 1.0f), ((f32x4*)out) + 2 * (size_t)i + 1);
    }
}

extern "C" void kernel_launch(void* const* d_in, const int* in_sizes, int n_in,
                              void* d_out, int out_size, void* d_ws, size_t ws_size,
                              hipStream_t stream) {
    const float* x   = (const float*)d_in[0];
    const float* ww0 = (const float*)d_in[1];
    const float* ww1 = (const float*)d_in[2];
    const float* ww2 = (const float*)d_in[3];
    const float* wb0 = (const float*)d_in[4];
    const float* wb1 = (const float*)d_in[5];
    const float* wb2 = (const float*)d_in[6];
    const float* hw0 = (const float*)d_in[7];
    const float* hw1 = (const float*)d_in[8];
    const float* hw2 = (const float*)d_in[9];
    const float* hb0 = (const float*)d_in[10];
    const float* hb1 = (const float*)d_in[11];
    const float* hb2 = (const float*)d_in[12];
    float* out = (float*)d_out;

    float* ws  = (float*)d_ws;
    int*   cnt = (int*)((char*)d_ws + CNT_BYTE_OFF);
    float* spatial = ws + SPA_OFF;

    // zero the per-batch arrival counters (deterministic per launch)
    hipMemsetAsync(cnt, 0, BB * sizeof(int), stream);

    reduce_branch_kernel<<<512, 256, 0, stream>>>(x,
            ww0, ww1, ww2, wb0, wb1, wb2,
            hw0, hw1, hw2, hb0, hb1, hb2,
            ws, cnt);
    apply_kernel<<<4096, 256, 0, stream>>>(x, spatial, out);
}

// Round 7
// 82.399 us; speedup vs baseline: 1.5409x; 1.5409x over previous
//
#include <hip/hip_runtime.h>
#include <float.h>

// Problem constants (match reference)
#define BB 32
#define CC 256
#define SS 64
#define IMG (SS * SS)          // 4096 pixels per (b,c) image
#define NPIX (BB * IMG)
#define NTOT (BB * CC * IMG)   // 33554432 total elements

typedef float f32x4 __attribute__((ext_vector_type(4)));

// ws layout (float offsets). Total 270336 floats = 1.06 MB (R1 proved >=1.5 MB available).
#define WPM_OFF 0              // wpart_max[32][16][2][64]  col-max partials (raw max over 128 ch, 4 rows)
#define WPS_OFF 65536          // wpart_sum[32][16][2][64]  col raw-sum partials
#define HPM_OFF 131072         // hpart_max[32][64][2]      row-max partials
#define HPS_OFF 135168         // hpart_sum[32][64][2]      row raw-sum partials
#define SPA_OFF 139264         // spatial[32][4096]

__device__ __forceinline__ f32x4 f4max(f32x4 a, f32x4 b) {
    f32x4 r;
    r.x = fmaxf(a.x, b.x); r.y = fmaxf(a.y, b.y);
    r.z = fmaxf(a.z, b.z); r.w = fmaxf(a.w, b.w);
    return r;
}
__device__ __forceinline__ f32x4 shfl_xor4(f32x4 v, int m) {
    f32x4 r;
    r.x = __shfl_xor(v.x, m); r.y = __shfl_xor(v.y, m);
    r.z = __shfl_xor(v.z, m); r.w = __shfl_xor(v.w, m);
    return r;
}
__device__ __forceinline__ float allreduce_sum(float v) {
#pragma unroll
    for (int o = 32; o > 0; o >>= 1) v += __shfl_xor(v, o);
    return v;
}
__device__ __forceinline__ float allreduce_max(float v) {
#pragma unroll
    for (int o = 32; o > 0; o >>= 1) v = fmaxf(v, __shfl_xor(v, o));
    return v;
}

__device__ __forceinline__ float branch_lane(float meanv, float maxv,
                                             float w0, float w1, float w2,
                                             float b0, float b1, float b2) {
    float m  = allreduce_max(meanv);
    float e  = expf(meanv - m);
    float s  = e / allreduce_sum(e);
    float y0 = allreduce_sum(meanv * w0);
    float y1 = allreduce_sum(maxv * w1);
    float y0t = tanhf(fmaf(y0, s, b0));
    float y1t = tanhf(fmaf(y1, s, b1));
    float yw2 = allreduce_sum(y1t * w2);
    return fmaf(yw2, y0t, b2);
}

// ---------------- Kernel 1: channel reduction -> tiny row/col partials ----------------
// 1024 blocks: blk = b*32 + j*2 + s.  b in [0,32), j in [0,16) pixel chunk
// (rows 4j..4j+3), s in [0,2) channel half.  Wave w reduces channels
// [s*128 + w*32, +32).  4 blocks/CU = 16 waves/CU (2x R1's occupancy).
// No fences, no atomics: the kernel boundary is the sync (R6 lesson).
__global__ __launch_bounds__(256) void reduce_part_kernel(const float* __restrict__ x,
                                                          float* __restrict__ ws) {
    const int blk  = blockIdx.x;
    const int b    = blk >> 5;
    const int j    = (blk & 31) >> 1;
    const int s    = blk & 1;
    const int tid  = threadIdx.x;
    const int wave = tid >> 6;
    const int lane = tid & 63;
    const int pos0 = j << 8;                       // 256 px = image rows 4j..4j+3

    const float* xp = x + ((size_t)(b * CC + s * 128 + wave * 32) << 12) + pos0 + (lane << 2);
    f32x4 vmax = (f32x4)(-FLT_MAX);
    f32x4 vsum = (f32x4)(0.f);
#pragma unroll 16
    for (int c = 0; c < 32; ++c) {
        f32x4 v = *(const f32x4*)(xp + ((size_t)c << 12));
        vmax = f4max(vmax, v);
        vsum += v;
    }

    __shared__ f32x4 smax[4][64];
    __shared__ f32x4 ssum[4][64];
    smax[wave][lane] = vmax;
    ssum[wave][lane] = vsum;
    __syncthreads();

    if (wave == 0) {
        f32x4 m  = smax[0][lane];
        f32x4 sm = ssum[0][lane];
#pragma unroll
        for (int w = 1; w < 4; ++w) {
            m  = f4max(m, smax[w][lane]);
            sm += ssum[w][lane];
        }
        // lane l holds pixels pos0+4l..4l+3: row = 4j + (l>>4), col = 4*(l&15)+k
        // Height partials: reduce over the 16 lanes of each row group.
        float em = fmaxf(fmaxf(m.x, m.y), fmaxf(m.z, m.w));
        float es = sm.x + sm.y + sm.z + sm.w;      // raw channel-sum (divide in K2)
#pragma unroll
        for (int o = 1; o < 16; o <<= 1) {
            em = fmaxf(em, __shfl_xor(em, o));
            es += __shfl_xor(es, o);
        }
        if ((lane & 15) == 0) {
            const int row = 4 * j + (lane >> 4);
            ws[HPM_OFF + (b * 64 + row) * 2 + s] = em;
            ws[HPS_OFF + (b * 64 + row) * 2 + s] = es;
        }
        // Width partials: combine the 4 row groups (xor 16, 32).
        f32x4 cm = m, cs = sm;
        cm = f4max(cm, shfl_xor4(cm, 16));
        cm = f4max(cm, shfl_xor4(cm, 32));
        cs += shfl_xor4(cs, 16);
        cs += shfl_xor4(cs, 32);
        if (lane < 16) {
            *(f32x4*)(ws + WPM_OFF + ((b * 16 + j) * 2 + s) * 64 + lane * 4) = cm;
            *(f32x4*)(ws + WPS_OFF + ((b * 16 + j) * 2 + s) * 64 + lane * 4) = cs;
        }
    }
}

// ---------------- Kernel 2: merge partials + branch + spatial tile ----------------
__global__ __launch_bounds__(64) void branch_kernel(
        const float* __restrict__ ws_in,
        const float* __restrict__ ww0, const float* __restrict__ ww1, const float* __restrict__ ww2,
        const float* __restrict__ wb0, const float* __restrict__ wb1, const float* __restrict__ wb2,
        const float* __restrict__ hw0, const float* __restrict__ hw1, const float* __restrict__ hw2,
        const float* __restrict__ hb0, const float* __restrict__ hb1, const float* __restrict__ hb2,
        float* __restrict__ spatial) {
    const int b = blockIdx.x;
    const int t = threadIdx.x;          // lane 0..63, one wave per batch

    // width: col t over all 16 chunks x 2 channel-halves (coalesced in t)
    float wm = -FLT_MAX, wsv = 0.f;
#pragma unroll 4
    for (int js = 0; js < 32; ++js) {
        wm  = fmaxf(wm, ws_in[WPM_OFF + (b * 32 + js) * 64 + t]);
        wsv += ws_in[WPS_OFF + (b * 32 + js) * 64 + t];
    }
    // height: row t over 2 channel-halves
    float hm = fmaxf(ws_in[HPM_OFF + (b * 64 + t) * 2], ws_in[HPM_OFF + (b * 64 + t) * 2 + 1]);
    float hs = ws_in[HPS_OFF + (b * 64 + t) * 2] + ws_in[HPS_OFF + (b * 64 + t) * 2 + 1];

    const float inv = 1.0f / (float)(CC * SS);     // raw sum -> mean over c and the spatial axis
    float y_w = branch_lane(wsv * inv, wm, ww0[t], ww1[t], ww2[t], wb0[t], wb1[t], wb2[t]);
    float y_h = branch_lane(hs * inv, hm, hw0[t], hw1[t], hw2[t], hb0[t], hb1[t], hb2[t]);

    __shared__ float sh_h[64];
    sh_h[t] = y_h;
    __syncthreads();

    float* sp = spatial + (size_t)b * IMG;
#pragma unroll 4
    for (int h = 0; h < 64; ++h) {
        sp[h * 64 + t] = tanhf(sh_h[h] * y_w);     // coalesced store
    }
}

// ---------------- Kernel 3: apply ----------------
__global__ __launch_bounds__(256) void apply_kernel(const float* __restrict__ x,
                                                    const float* __restrict__ spatial,
                                                    float* __restrict__ out) {
    const int nPairs = NTOT / 8;
    const int stride = gridDim.x * blockDim.x;
    for (int i = blockIdx.x * blockDim.x + threadIdx.x; i < nPairs; i += stride) {
        const size_t e = (size_t)i << 3;               // float index (multiple of 8)
        f32x4 xa = ((const f32x4*)x)[2 * (size_t)i];
        f32x4 xb = ((const f32x4*)x)[2 * (size_t)i + 1];
        const size_t b   = e >> 20;                    // / (C*IMG)
        const size_t pos = e & (IMG - 1);              // within image (IMG%8==0: no crossing)
        const float* spp = spatial + (b << 12) + pos;
        f32x4 sa = *(const f32x4*)(spp);
        f32x4 sb = *(const f32x4*)(spp + 4);
        __builtin_nontemporal_store(xa * (sa + 1.0f), ((f32x4*)out) + 2 * (size_t)i);
        __builtin_nontemporal_store(xb * (sb + 1.0f), ((f32x4*)out) + 2 * (size_t)i + 1);
    }
}

extern "C" void kernel_launch(void* const* d_in, const int* in_sizes, int n_in,
                              void* d_out, int out_size, void* d_ws, size_t ws_size,
                              hipStream_t stream) {
    const float* x   = (const float*)d_in[0];
    const float* ww0 = (const float*)d_in[1];
    const float* ww1 = (const float*)d_in[2];
    const float* ww2 = (const float*)d_in[3];
    const float* wb0 = (const float*)d_in[4];
    const float* wb1 = (const float*)d_in[5];
    const float* wb2 = (const float*)d_in[6];
    const float* hw0 = (const float*)d_in[7];
    const float* hw1 = (const float*)d_in[8];
    const float* hw2 = (const float*)d_in[9];
    const float* hb0 = (const float*)d_in[10];
    const float* hb1 = (const float*)d_in[11];
    const float* hb2 = (const float*)d_in[12];
    float* out = (float*)d_out;

    float* ws      = (float*)d_ws;
    float* spatial = ws + SPA_OFF;

    reduce_part_kernel<<<1024, 256, 0, stream>>>(x, ws);
    branch_kernel<<<BB, 64, 0, stream>>>(ws,
            ww0, ww1, ww2, wb0, wb1, wb2,
            hw0, hw1, hw2, hb0, hb1, hb2, spatial);
    apply_kernel<<<4096, 256, 0, stream>>>(x, spatial, out);
}

// Round 9
// 68.596 us; speedup vs baseline: 1.8510x; 1.2012x over previous
//
#include <hip/hip_runtime.h>
#include <float.h>

// Problem constants (match reference)
#define BB 32
#define CC 256
#define SS 64
#define IMG (SS * SS)          // 4096 pixels per (b,c) image
#define NTOT (BB * CC * IMG)   // 33554432 total elements

typedef float f32x4 __attribute__((ext_vector_type(4)));

// ws layout (float offsets) — partials only, ~280 KB
#define WPM_OFF 0              // wpart_max[32][16][64]  col-max partials (full 256 ch, rows 4j..4j+3)
#define WPS_OFF 32768          // wpart_sum[32][16][64]  col mean-sum partials
#define HMX_OFF 65536          // hmax[32][64]           complete per-row max
#define HSM_OFF 67584          // hsum[32][64]           complete per-row mean-sum

__device__ __forceinline__ f32x4 f4max(f32x4 a, f32x4 b) {
    f32x4 r;
    r.x = fmaxf(a.x, b.x); r.y = fmaxf(a.y, b.y);
    r.z = fmaxf(a.z, b.z); r.w = fmaxf(a.w, b.w);
    return r;
}
__device__ __forceinline__ f32x4 shfl_xor4(f32x4 v, int m) {
    f32x4 r;
    r.x = __shfl_xor(v.x, m); r.y = __shfl_xor(v.y, m);
    r.z = __shfl_xor(v.z, m); r.w = __shfl_xor(v.w, m);
    return r;
}
__device__ __forceinline__ float allreduce_sum(float v) {
#pragma unroll
    for (int o = 32; o > 0; o >>= 1) v += __shfl_xor(v, o);
    return v;
}
__device__ __forceinline__ float allreduce_max(float v) {
#pragma unroll
    for (int o = 32; o > 0; o >>= 1) v = fmaxf(v, __shfl_xor(v, o));
    return v;
}

__device__ __forceinline__ float branch_lane(float meanv, float maxv,
                                             float w0, float w1, float w2,
                                             float b0, float b1, float b2) {
    float m  = allreduce_max(meanv);
    float e  = expf(meanv - m);
    float s  = e / allreduce_sum(e);
    float y0 = allreduce_sum(meanv * w0);
    float y1 = allreduce_sum(maxv * w1);
    float y0t = tanhf(fmaf(y0, s, b0));
    float y1t = tanhf(fmaf(y1, s, b1));
    float yw2 = allreduce_sum(y1t * w2);
    return fmaf(yw2, y0t, b2);
}

// ---------------- Kernel 1: channel reduction -> tiny partials ----------------
// 512 blocks: b = blk>>4, chunk j = blk&15 (rows 4j..4j+3 = 256 px).
// Wave w reduces channels [w*64, +64); LDS merge; wave 0 emits:
//   - complete height rows  (hmax/hsum per row)
//   - per-chunk width col partials (wpart over the 4 rows)
// Verified logic (R6 phase A / R7), fence-free.
__global__ __launch_bounds__(256) void reduce_part_kernel(const float* __restrict__ x,
                                                          float* __restrict__ ws) {
    const int blk  = blockIdx.x;
    const int b    = blk >> 4;
    const int j    = blk & 15;
    const int tid  = threadIdx.x;
    const int wave = tid >> 6;
    const int lane = tid & 63;
    const int pos0 = j << 8;

    const float* xp = x + ((size_t)(b * CC + wave * 64) << 12) + pos0 + (lane << 2);
    f32x4 vmax = (f32x4)(-FLT_MAX);
    f32x4 vsum = (f32x4)(0.f);
#pragma unroll 16
    for (int c = 0; c < 64; ++c) {
        f32x4 v = *(const f32x4*)(xp + ((size_t)c << 12));
        vmax = f4max(vmax, v);
        vsum += v;
    }

    __shared__ f32x4 smax[4][64];
    __shared__ f32x4 ssum[4][64];
    smax[wave][lane] = vmax;
    ssum[wave][lane] = vsum;
    __syncthreads();

    if (wave == 0) {
        f32x4 m  = smax[0][lane];
        f32x4 sm = ssum[0][lane];
#pragma unroll
        for (int w = 1; w < 4; ++w) {
            m  = f4max(m, smax[w][lane]);
            sm += ssum[w][lane];
        }
        f32x4 mean = sm * (1.0f / (float)CC);

        // lane l: row = 4j + (l>>4), cols 4*(l&15)+k
        // Height (complete rows): reduce over the 16 lanes of each row group.
        float em = fmaxf(fmaxf(m.x, m.y), fmaxf(m.z, m.w));
        float es = mean.x + mean.y + mean.z + mean.w;
#pragma unroll
        for (int o = 1; o < 16; o <<= 1) {
            em = fmaxf(em, __shfl_xor(em, o));
            es += __shfl_xor(es, o);
        }
        if ((lane & 15) == 0) {
            const int row = 4 * j + (lane >> 4);
            ws[HMX_OFF + b * 64 + row] = em;
            ws[HSM_OFF + b * 64 + row] = es;
        }
        // Width partials over this chunk's 4 rows.
        f32x4 cm = m, cs = mean;
        cm = f4max(cm, shfl_xor4(cm, 16));
        cm = f4max(cm, shfl_xor4(cm, 32));
        cs += shfl_xor4(cs, 16);
        cs += shfl_xor4(cs, 32);
        if (lane < 16) {
            *(f32x4*)(ws + WPM_OFF + (b * 16 + j) * 64 + lane * 4) = cm;
            *(f32x4*)(ws + WPS_OFF + (b * 16 + j) * 64 + lane * 4) = cs;
        }
    }
}

// ---------------- Kernel 2: branch (from partials) + apply, fused ----------------
// 1024 blocks: b = blk>>5, channel group g = blk&31 (channels 8g..8g+7).
// Each block redundantly re-derives y_w/y_h from the 8.5 KB partials (L2-hot),
// builds the 4096-px (tanh+1) tile in LDS once, then streams its 8 channels.
__global__ __launch_bounds__(256) void branch_apply_kernel(
        const float* __restrict__ x, const float* __restrict__ ws,
        const float* __restrict__ ww0, const float* __restrict__ ww1, const float* __restrict__ ww2,
        const float* __restrict__ wb0, const float* __restrict__ wb1, const float* __restrict__ wb2,
        const float* __restrict__ hw0, const float* __restrict__ hw1, const float* __restrict__ hw2,
        const float* __restrict__ hb0, const float* __restrict__ hb1, const float* __restrict__ hb2,
        float* __restrict__ out) {
    const int blk  = blockIdx.x;
    const int b    = blk >> 5;
    const int g    = blk & 31;
    const int tid  = threadIdx.x;
    const int wave = tid >> 6;
    const int lane = tid & 63;

    __shared__ float sh_w[64], sh_h[64];
    if (wave == 0) {
        float wm = -FLT_MAX, wsv = 0.f;
#pragma unroll 4
        for (int j = 0; j < 16; ++j) {
            wm  = fmaxf(wm, ws[WPM_OFF + (b * 16 + j) * 64 + lane]);
            wsv += ws[WPS_OFF + (b * 16 + j) * 64 + lane];
        }
        sh_w[lane] = branch_lane(wsv * (1.0f / (float)SS), wm,
                                 ww0[lane], ww1[lane], ww2[lane],
                                 wb0[lane], wb1[lane], wb2[lane]);
    } else if (wave == 1) {
        float hm = ws[HMX_OFF + b * 64 + lane];
        float hs = ws[HSM_OFF + b * 64 + lane];
        sh_h[lane] = branch_lane(hs * (1.0f / (float)SS), hm,
                                 hw0[lane], hw1[lane], hw2[lane],
                                 hb0[lane], hb1[lane], hb2[lane]);
    }
    __syncthreads();

    // (tanh+1) tile, computed once per block, reused by 8 channels.
    __shared__ float sp[IMG];          // 16 KiB
#pragma unroll 4
    for (int p = tid; p < IMG; p += 256) {
        sp[p] = tanhf(sh_h[p >> 6] * sh_w[p & 63]) + 1.0f;
    }
    __syncthreads();

    const float* xp = x   + ((size_t)(b * CC + g * 8) << 12);
    float*       op = out + ((size_t)(b * CC + g * 8) << 12);
#pragma unroll
    for (int c = 0; c < 8; ++c) {
        const f32x4* xc = (const f32x4*)(xp + ((size_t)c << 12));
        f32x4*       oc = (f32x4*)(op + ((size_t)c << 12));
#pragma unroll
        for (int p4 = tid; p4 < IMG / 4; p4 += 256) {
            f32x4 v = xc[p4];
            f32x4 s = *(const f32x4*)(sp + p4 * 4);   // ds_read_b128, conflict-free
            __builtin_nontemporal_store(v * s, oc + p4);
        }
    }
}

extern "C" void kernel_launch(void* const* d_in, const int* in_sizes, int n_in,
                              void* d_out, int out_size, void* d_ws, size_t ws_size,
                              hipStream_t stream) {
    const float* x   = (const float*)d_in[0];
    const float* ww0 = (const float*)d_in[1];
    const float* ww1 = (const float*)d_in[2];
    const float* ww2 = (const float*)d_in[3];
    const float* wb0 = (const float*)d_in[4];
    const float* wb1 = (const float*)d_in[5];
    const float* wb2 = (const float*)d_in[6];
    const float* hw0 = (const float*)d_in[7];
    const float* hw1 = (const float*)d_in[8];
    const float* hw2 = (const float*)d_in[9];
    const float* hb0 = (const float*)d_in[10];
    const float* hb1 = (const float*)d_in[11];
    const float* hb2 = (const float*)d_in[12];
    float* out = (float*)d_out;
    float* ws  = (float*)d_ws;

    reduce_part_kernel<<<512, 256, 0, stream>>>(x, ws);
    branch_apply_kernel<<<1024, 256, 0, stream>>>(x, ws,
            ww0, ww1, ww2, wb0, wb1, wb2,
            hw0, hw1, hw2, hb0, hb1, hb2, out);
}